// Round 11
// baseline (140.014 us; speedup 1.0000x reference)
//
#include <hip/hip_runtime.h>

// ---------------------------------------------------------------------------
// TimeLSTMCell fused kernel for MI355X (gfx950) — round 13
// B=4096, D=256, U=512; out = concat(h, c_m) fp32
//
// ROUND 13: single launch with a CONTENTION-FREE flags barrier.
//   r12's 118us regression was diagnosed as 512 contended release-RMWs on ONE
//   cache line across 8 XCDs (~0.25us each serialized = ~120us). Fix:
//   - arrive: block b release-stores 1 to its OWN word flags[b] (512 distinct
//     lines -> parallel, zero contention, no RMW).
//   - wait: wave 0 only; lane l acquire-polls flags[l*8..l*8+7] with s_sleep
//     between sweeps (acquire@agent = L1/L2 inv -> sees remote XCD stores).
//   - prep phase: contiguous 1120-chunk range per block (uniform branching),
//     byte-identical output to r6 prep.
//   - main body: r6 VERBATIM (128x32 tile, 4 waves 2x2, BK=64, dbuf 72KB,
//     counted-vmcnt 12-step loop, validated epilogue).
//   - grid 512 x 256thr, 72KB LDS -> exactly 2 blocks/CU x 256 CU = full
//     co-residency (confirmed by r12's occupancy row) -> no deadlock.
//   - ws_size guard falls back to the exact two-launch r6 path.
//   Theory: the 2240-block prep dispatch stream + inter-dispatch drain is the
//   ~5-10us no intra-kernel lever could touch (10 rounds flat at ~33).
// ---------------------------------------------------------------------------

typedef __attribute__((ext_vector_type(8))) short short8_t;   // 8 bf16
typedef __attribute__((ext_vector_type(4))) float f32x4_t;
typedef unsigned int u32;

#define B_N 4096
#define D_K 256
#define U_N 512

__device__ __forceinline__ unsigned short f2bf(float f) {
    unsigned int x = __float_as_uint(f);
    unsigned int r = x + 0x7fffu + ((x >> 16) & 1u);   // RNE
    return (unsigned short)(r >> 16);
}

__device__ __forceinline__ float sigf(float z) {
    return 1.0f / (1.0f + __expf(-z));
}

// fast tanh: exact at +/-inf, ~1e-7 abs err
__device__ __forceinline__ float tanhfast(float z) {
    return 1.0f - 2.0f / (1.0f + __expf(2.0f * z));
}

__device__ __forceinline__ void gl16(const unsigned short* g, unsigned short* l) {
    __builtin_amdgcn_global_load_lds(
        (const __attribute__((address_space(1))) u32*)g,
        (__attribute__((address_space(3))) u32*)l, 16, 0, 0);
}

// swizzled element offset of (row r, k-chunk kc) inside a tile with 8 chunks/row
#define SWZ(r, kc) ((((r) * 8) + ((kc) ^ ((r) & 7))) * 8)

// counted vmcnt wait + scheduling fence (compile-time literal N)
#define WAIT_VM(N)                                            \
    asm volatile("s_waitcnt vmcnt(" #N ")" ::: "memory");     \
    __builtin_amdgcn_sched_barrier(0)

// ---------------------------------------------------------------------------
// prep work item (r6 verbatim): one 16B bf16 chunk per call
//   x  : 131072 chunks -> tiles (rb 0..31, kb 0..3)  of 128x64
//   h0 : 262144 chunks -> tiles (rb 0..31, kb 0..7)  of 128x64
//   ker:  81920 chunks -> tiles (nb 0..15, kb 0..3)  of 160x64 (transposed)
//   rk :  98304 chunks -> tiles (nb 0..15, kb 0..7)  of  96x64 (transposed)
// total 573440 chunks
// ---------------------------------------------------------------------------
__device__ __forceinline__ void prep_chunk(int c,
    const float* __restrict__ x, const float* __restrict__ h0,
    const float* __restrict__ kern, const float* __restrict__ rk,
    unsigned short* __restrict__ xs, unsigned short* __restrict__ hs,
    unsigned short* __restrict__ ksw, unsigned short* __restrict__ rsw)
{
    if (c < 131072) {                       // ---- x ----
        const int t = c >> 10, q = c & 1023;
        const int row = q >> 3, kc = q & 7;
        const int rb = t >> 2, kb = t & 3;
        const float* s = x + (size_t)(rb * 128 + row) * D_K + kb * 64 + kc * 8;
        short8_t o;
#pragma unroll
        for (int j = 0; j < 8; ++j) o[j] = (short)f2bf(s[j]);
        *reinterpret_cast<short8_t*>(xs + (size_t)t * 8192 + SWZ(row, kc)) = o;
    } else if (c < 393216) {                // ---- h0 ----
        const int c2 = c - 131072;
        const int t = c2 >> 10, q = c2 & 1023;
        const int row = q >> 3, kc = q & 7;
        const int rb = t >> 3, kb = t & 7;
        const float* s = h0 + (size_t)(rb * 128 + row) * U_N + kb * 64 + kc * 8;
        short8_t o;
#pragma unroll
        for (int j = 0; j < 8; ++j) o[j] = (short)f2bf(s[j]);
        *reinterpret_cast<short8_t*>(hs + (size_t)t * 8192 + SWZ(row, kc)) = o;
    } else if (c < 475136) {                // ---- kernel (transpose) ----
        const int c2 = c - 393216;
        const int t = c2 / 1280, q = c2 - t * 1280;
        const int kc = q / 160, r = q - kc * 160;     // r = mat*32 + cc
        const int nb = t >> 2, kb = t & 3;
        const int col = (r >> 5) * U_N + nb * 32 + (r & 31);
        short8_t o;
#pragma unroll
        for (int j = 0; j < 8; ++j)
            o[j] = (short)f2bf(kern[(size_t)(kb * 64 + kc * 8 + j) * 2560 + col]);
        *reinterpret_cast<short8_t*>(ksw + (size_t)t * 10240 + SWZ(r, kc)) = o;
    } else {                                // ---- rk (transpose) ----
        const int c2 = c - 475136;
        const int t = c2 / 768, q = c2 - t * 768;
        const int kc = q / 96, r = q - kc * 96;       // r = mat*32 + cc
        const int nb = t >> 3, kb = t & 7;
        const int col = (r >> 5) * U_N + nb * 32 + (r & 31);
        short8_t o;
#pragma unroll
        for (int j = 0; j < 8; ++j)
            o[j] = (short)f2bf(rk[(size_t)(kb * 64 + kc * 8 + j) * 1536 + col]);
        *reinterpret_cast<short8_t*>(rsw + (size_t)t * 6144 + SWZ(r, kc)) = o;
    }
}

// standalone prep kernel (fallback path only) — r6 verbatim behavior
__global__ __launch_bounds__(256) void prep(
    const float* __restrict__ x, const float* __restrict__ h0,
    const float* __restrict__ kern, const float* __restrict__ rk,
    unsigned short* __restrict__ xs, unsigned short* __restrict__ hs,
    unsigned short* __restrict__ ksw, unsigned short* __restrict__ rsw)
{
    const int c = blockIdx.x * 256 + threadIdx.x;
    if (c < 573440)
        prep_chunk(c, x, h0, kern, rk, xs, hs, ksw, rsw);
}

// ---------------------------------------------------------------------------
// fused kernel: [optional prep phase + flags grid barrier] + r6 main body
// grid 512 (1-D; nb = bid & 15, rb = bid >> 4), 256 threads (4 waves)
// ---------------------------------------------------------------------------
__global__ __launch_bounds__(256, 2) void tlstm_fused(
    const float* __restrict__ x,              // [4096][256]
    const float* __restrict__ h0,             // [4096][512]
    const float* __restrict__ kern,           // [256][2560]
    const float* __restrict__ rk,             // [512][1536]
    unsigned short* __restrict__ xs, unsigned short* __restrict__ hs,
    unsigned short* __restrict__ ksw, unsigned short* __restrict__ rsw,
    const float* __restrict__ tvec,           // [4096]
    const float* __restrict__ c0,             // [4096][512]
    const float* __restrict__ ktime,          // [1536] cols [t1,t2,o]
    float* __restrict__ out,                  // h, then c_m
    unsigned int* __restrict__ flags,         // [512] arrival flags (zeroed)
    int do_prep)
{
    // per buffer: A 8192 elems (16KB) + B 10240 elems (20KB) = 36KB; x2 = 72KB
    __shared__ __align__(16) unsigned short lds[2][18432];

    const int tid = threadIdx.x;
    const int bid = blockIdx.x;
    const int wave = tid >> 6;
    const int lane = tid & 63;

    if (do_prep) {
        // ---- phase 0: prep — contiguous 1120-chunk range per block ----
        const int base = bid * 1120;
#pragma unroll 1
        for (int r = 0; r < 5; ++r) {
            const int off = r * 256 + tid;
            if (off < 1120)
                prep_chunk(base + off, x, h0, kern, rk, xs, hs, ksw, rsw);
        }
        // ---- flags grid barrier (512 co-resident blocks, 2/CU) ----
        asm volatile("s_waitcnt vmcnt(0)" ::: "memory");  // drain my stores
        __threadfence();                                  // agent release fence
        __syncthreads();
        if (tid == 0)
            __hip_atomic_store(&flags[bid], 1u, __ATOMIC_RELEASE,
                               __HIP_MEMORY_SCOPE_AGENT);
        if (wave == 0) {
            // lane l polls flags[l*8 .. l*8+7]; acquire = L1/L2 inv per sweep
            unsigned int pend = 0xffu;
#pragma unroll 1
            while (pend) {
#pragma unroll
                for (int k = 0; k < 8; ++k)
                    if (pend & (1u << k))
                        if (__hip_atomic_load(&flags[lane * 8 + k],
                                              __ATOMIC_ACQUIRE,
                                              __HIP_MEMORY_SCOPE_AGENT))
                            pend &= ~(1u << k);
                if (pend) __builtin_amdgcn_s_sleep(8);
            }
        }
        __syncthreads();   // all waves held until wave 0 saw all 512 arrivals
    }

    // ---- phase 1: main (r6 body verbatim) ----
    const int lr = lane & 15;
    const int lq = lane >> 4;
    const int wm = wave >> 1;                 // 0..1 : row half
    const int wn = wave & 1;                  // 0..1 : col half
    const int nb = bid & 15;
    const int rb = bid >> 4;

    // acc[m][p]: gate m (0..4 = x@K gates, 5..7 = h0@RK gates),
    // row-fragment p (rows wm*64 + p*16), cols wn*16..+16
    f32x4_t acc[8][4];
#pragma unroll
    for (int m = 0; m < 8; ++m)
#pragma unroll
        for (int p = 0; p < 4; ++p)
            acc[m][p] = (f32x4_t){0.f, 0.f, 0.f, 0.f};

    // ---- staging: linear global_load_lds, wave-uniform LDS dest ----
    // per-thread vmem ops: phase1 (s<4): 4 A + 5 B = 9; phase2: 4 A + 3 B = 7
    auto stage = [&](int s, int buf) {
        unsigned short* ab = &lds[buf][0];
        unsigned short* bb = &lds[buf][8192];
        if (s < 4) {
            const unsigned short* at = xs + (size_t)(rb * 4 + s) * 8192;
#pragma unroll
            for (int j = 0; j < 4; ++j)
                gl16(at + (j * 256 + tid) * 8, ab + (j * 256 + wave * 64) * 8);
            const unsigned short* bt = ksw + (size_t)(nb * 4 + s) * 10240;
#pragma unroll
            for (int j = 0; j < 5; ++j)
                gl16(bt + (j * 256 + tid) * 8, bb + (j * 256 + wave * 64) * 8);
        } else {
            const unsigned short* at = hs + (size_t)(rb * 8 + (s - 4)) * 8192;
#pragma unroll
            for (int j = 0; j < 4; ++j)
                gl16(at + (j * 256 + tid) * 8, ab + (j * 256 + wave * 64) * 8);
            const unsigned short* bt = rsw + (size_t)(nb * 8 + (s - 4)) * 6144;
#pragma unroll
            for (int j = 0; j < 3; ++j)
                gl16(bt + (j * 256 + tid) * 8, bb + (j * 256 + wave * 64) * 8);
        }
    };

    auto compute1 = [&](int buf) {      // x @ kernel -> acc[0..4]
        const unsigned short* ab = &lds[buf][0];
        const unsigned short* bb = &lds[buf][8192];
#pragma unroll
        for (int ks = 0; ks < 2; ++ks) {
            const int kc = ks * 4 + lq;
            short8_t a[4];
#pragma unroll
            for (int p = 0; p < 4; ++p)
                a[p] = *reinterpret_cast<const short8_t*>(ab + SWZ(wm * 64 + p * 16 + lr, kc));
#pragma unroll
            for (int m = 0; m < 5; ++m) {
                const int r = m * 32 + wn * 16 + lr;
                short8_t b = *reinterpret_cast<const short8_t*>(bb + SWZ(r, kc));
#pragma unroll
                for (int p = 0; p < 4; ++p)
                    acc[m][p] = __builtin_amdgcn_mfma_f32_16x16x32_bf16(a[p], b, acc[m][p], 0, 0, 0);
            }
        }
    };

    auto compute2 = [&](int buf) {      // h0 @ rk -> acc[5..7]
        const unsigned short* ab = &lds[buf][0];
        const unsigned short* bb = &lds[buf][8192];
#pragma unroll
        for (int ks = 0; ks < 2; ++ks) {
            const int kc = ks * 4 + lq;
            short8_t a[4];
#pragma unroll
            for (int p = 0; p < 4; ++p)
                a[p] = *reinterpret_cast<const short8_t*>(ab + SWZ(wm * 64 + p * 16 + lr, kc));
#pragma unroll
            for (int m = 0; m < 3; ++m) {
                const int r = m * 32 + wn * 16 + lr;
                short8_t b = *reinterpret_cast<const short8_t*>(bb + SWZ(r, kc));
#pragma unroll
                for (int p = 0; p < 4; ++p)
                    acc[5 + m][p] = __builtin_amdgcn_mfma_f32_16x16x32_bf16(a[p], b, acc[5 + m][p], 0, 0, 0);
            }
        }
    };

    // step body for tile S: wait until tile S's loads landed (leave the NV
    // just-issued loads of tile S+1 in flight), sync, compute, sync.
#define K_BODY(S, NV, CF)                                  \
    {                                                      \
        WAIT_VM(NV);                                       \
        __builtin_amdgcn_s_barrier();                      \
        __builtin_amdgcn_sched_barrier(0);                 \
        CF((S) & 1);                                       \
        __builtin_amdgcn_sched_barrier(0);                 \
        __builtin_amdgcn_s_barrier();                      \
        __builtin_amdgcn_sched_barrier(0);                 \
    }

    // ---- counted-vmcnt pipelined K-loop: 12 steps ----
    // per-thread load counts: L = [9,9,9,9,7,7,7,7,7,7,7,7]
    stage(0, 0);
    stage(1, 1);   K_BODY(0, 9, compute1);
    stage(2, 0);   K_BODY(1, 9, compute1);
    stage(3, 1);   K_BODY(2, 9, compute1);
    stage(4, 0);   K_BODY(3, 7, compute1);
    stage(5, 1);   K_BODY(4, 7, compute2);
    stage(6, 0);   K_BODY(5, 7, compute2);
    stage(7, 1);   K_BODY(6, 7, compute2);
    stage(8, 0);   K_BODY(7, 7, compute2);
    stage(9, 1);   K_BODY(8, 7, compute2);
    stage(10, 0);  K_BODY(9, 7, compute2);
    stage(11, 1);  K_BODY(10, 7, compute2);
    K_BODY(11, 0, compute2);

    // ---- epilogue: TimeLSTM elementwise (fp32) ----
    // t1_constraint: sigmoid output is always > -1e-5 -> constant -1e-5.
    const float NEG_EPS = -1e-5f;
    const int u = nb * 32 + wn * 16 + lr;
    const float kt1 = ktime[u];
    const float kt2 = ktime[U_N + u];
    const float kto = ktime[2 * U_N + u];
#pragma unroll
    for (int p = 0; p < 4; ++p)
#pragma unroll
        for (int i2 = 0; i2 < 4; ++i2) {
            const int b = rb * 128 + wm * 64 + p * 16 + lq * 4 + i2;
            const float tb = tvec[b];
            const float c0v = c0[(size_t)b * U_N + u];
            const float x_i  = acc[0][p][i2];
            const float x_c  = acc[1][p][i2];
            const float x_o  = acc[2][p][i2];
            const float x_t1 = acc[3][p][i2];
            const float x_t2 = acc[4][p][i2];
            const float r_i  = acc[5][p][i2];
            const float r_c  = acc[6][p][i2];
            const float r_o  = acc[7][p][i2];

            const float ig  = sigf(x_i + r_i);
            const float t1v = sigf(x_t1 + sigf(tb * kt1));
            const float t2v = sigf(x_t2 + sigf(tb * kt2));
            const float ct  = tanhfast(x_c + r_c);
            const float cm_ = (1.f - ig * t1v) * c0v + ig * ct * NEG_EPS;
            const float cm  = (1.f - ig) * c0v + ig * ct * t2v;
            const float og  = sigf(x_o + r_o + tb * kto);

            out[(size_t)b * U_N + u] = tanhfast(cm_) * og;
            out[(size_t)B_N * U_N + (size_t)b * U_N + u] = cm;
        }
}

// ---------------------------------------------------------------------------
extern "C" void kernel_launch(void* const* d_in, const int* in_sizes, int n_in,
                              void* d_out, int out_size, void* d_ws, size_t ws_size,
                              hipStream_t stream) {
    const float* x     = (const float*)d_in[0];   // [4096][256]
    const float* t     = (const float*)d_in[1];   // [4096][1]
    const float* h0    = (const float*)d_in[2];   // [4096][512]
    const float* c0    = (const float*)d_in[3];   // [4096][512]
    const float* kern  = (const float*)d_in[4];   // [256][2560]
    const float* rk    = (const float*)d_in[5];   // [512][1536]
    const float* ktime = (const float*)d_in[6];   // [1][1536]
    float* out = (float*)d_out;

    // ws layout (bytes):
    //   xs    @ 0        : 4096*256*2  = 2,097,152  (swizzled 128x64 tiles)
    //   hs    @ 2097152  : 4096*512*2  = 4,194,304
    //   ksw   @ 6291456  : 2560*256*2  = 1,310,720  (swizzled 160x64 tiles)
    //   rsw   @ 7602176  : 1536*512*2  = 1,572,864  (swizzled  96x64 tiles)
    //   flags @ 9175040  : 512*4 = 2048 (grid-barrier arrival flags)
    unsigned short* xs  = (unsigned short*)d_ws;
    unsigned short* hs  = (unsigned short*)((char*)d_ws + 2097152);
    unsigned short* ksw = (unsigned short*)((char*)d_ws + 6291456);
    unsigned short* rsw = (unsigned short*)((char*)d_ws + 7602176);
    const size_t FLAGS_OFF = 9175040;
    unsigned int* flags = (unsigned int*)((char*)d_ws + FLAGS_OFF);

    if (ws_size >= FLAGS_OFF + 2048) {
        // single-launch path: zero arrival flags, then fused kernel
        hipMemsetAsync((char*)d_ws + FLAGS_OFF, 0, 2048, stream);
        tlstm_fused<<<512, 256, 0, stream>>>(
            x, h0, kern, rk, xs, hs, ksw, rsw, t, c0, ktime, out, flags, 1);
    } else {
        // fallback: exact r6 two-launch path
        prep<<<2240, 256, 0, stream>>>(x, h0, kern, rk, xs, hs, ksw, rsw);
        tlstm_fused<<<512, 256, 0, stream>>>(
            x, h0, kern, rk, xs, hs, ksw, rsw, t, c0, ktime, out, flags, 0);
    }
}

// Round 12
// 32.532 us; speedup vs baseline: 4.3038x; 4.3038x over previous
//
#include <hip/hip_runtime.h>

// ---------------------------------------------------------------------------
// TimeLSTMCell fused kernel for MI355X (gfx950) — round 14
// B=4096, D=256, U=512; out = concat(h, c_m) fp32
//
// ROUND 14: REVERT to the measured-best r6 structure (32.7us: two launches,
//   128x32 tile, 4 waves 2x2, BK=64, dbuf 72KB LDS, 2 blocks/CU, counted-
//   vmcnt 12-step loop) + two isolated, validated micro-deltas:
//   1. c0 prefetch: 16 scalar c0 loads issued after stage(11) (order pinned
//      by sched_barrier); vmcnt counts extended (K10 waits 23, K11 waits 16)
//      -> the 8MB c0 read hides under the last two compute steps instead of
//      stalling the epilogue.
//   2. NEG_EPS fold: sigmoid > -1e-5 always, so the reference where() always
//      picks the constant (validated bit-exact r9-r13).
//   Single-launch fusion abandoned: three implementations failed (coop API
//   no-op r8; contended-counter 118us r12; flags barrier 140us r13 with a
//   41ms replay dispatch = co-residency NOT guaranteed under this harness).
// ---------------------------------------------------------------------------

typedef __attribute__((ext_vector_type(8))) short short8_t;   // 8 bf16
typedef __attribute__((ext_vector_type(4))) float f32x4_t;
typedef unsigned int u32;

#define B_N 4096
#define D_K 256
#define U_N 512

__device__ __forceinline__ unsigned short f2bf(float f) {
    unsigned int x = __float_as_uint(f);
    unsigned int r = x + 0x7fffu + ((x >> 16) & 1u);   // RNE
    return (unsigned short)(r >> 16);
}

__device__ __forceinline__ float sigf(float z) {
    return 1.0f / (1.0f + __expf(-z));
}

// fast tanh: exact at +/-inf, ~1e-7 abs err
__device__ __forceinline__ float tanhfast(float z) {
    return 1.0f - 2.0f / (1.0f + __expf(2.0f * z));
}

__device__ __forceinline__ void gl16(const unsigned short* g, unsigned short* l) {
    __builtin_amdgcn_global_load_lds(
        (const __attribute__((address_space(1))) u32*)g,
        (__attribute__((address_space(3))) u32*)l, 16, 0, 0);
}

// swizzled element offset of (row r, k-chunk kc) inside a tile with 8 chunks/row
#define SWZ(r, kc) ((((r) * 8) + ((kc) ^ ((r) & 7))) * 8)

// counted vmcnt wait + scheduling fence (compile-time literal N)
#define WAIT_VM(N)                                            \
    asm volatile("s_waitcnt vmcnt(" #N ")" ::: "memory");     \
    __builtin_amdgcn_sched_barrier(0)

// ---------------------------------------------------------------------------
// prepass (r6 verbatim): 4 segments by flat chunk id (16B bf16 chunk each)
//   x  : 131072 chunks -> tiles (rb 0..31, kb 0..3)  of 128x64
//   h0 : 262144 chunks -> tiles (rb 0..31, kb 0..7)  of 128x64
//   ker:  81920 chunks -> tiles (nb 0..15, kb 0..3)  of 160x64 (transposed)
//   rk :  98304 chunks -> tiles (nb 0..15, kb 0..7)  of  96x64 (transposed)
// total 573440 chunks = 2240 blocks x 256
// ---------------------------------------------------------------------------
__global__ __launch_bounds__(256) void prep(
    const float* __restrict__ x, const float* __restrict__ h0,
    const float* __restrict__ kern, const float* __restrict__ rk,
    unsigned short* __restrict__ xs, unsigned short* __restrict__ hs,
    unsigned short* __restrict__ ksw, unsigned short* __restrict__ rsw)
{
    const int c = blockIdx.x * 256 + threadIdx.x;
    if (c < 131072) {                       // ---- x ----
        const int t = c >> 10, q = c & 1023;
        const int row = q >> 3, kc = q & 7;
        const int rb = t >> 2, kb = t & 3;
        const float* s = x + (size_t)(rb * 128 + row) * D_K + kb * 64 + kc * 8;
        short8_t o;
#pragma unroll
        for (int j = 0; j < 8; ++j) o[j] = (short)f2bf(s[j]);
        *reinterpret_cast<short8_t*>(xs + (size_t)t * 8192 + SWZ(row, kc)) = o;
    } else if (c < 393216) {                // ---- h0 ----
        const int c2 = c - 131072;
        const int t = c2 >> 10, q = c2 & 1023;
        const int row = q >> 3, kc = q & 7;
        const int rb = t >> 3, kb = t & 7;
        const float* s = h0 + (size_t)(rb * 128 + row) * U_N + kb * 64 + kc * 8;
        short8_t o;
#pragma unroll
        for (int j = 0; j < 8; ++j) o[j] = (short)f2bf(s[j]);
        *reinterpret_cast<short8_t*>(hs + (size_t)t * 8192 + SWZ(row, kc)) = o;
    } else if (c < 475136) {                // ---- kernel (transpose) ----
        const int c2 = c - 393216;
        const int t = c2 / 1280, q = c2 - t * 1280;
        const int kc = q / 160, r = q - kc * 160;     // r = mat*32 + cc
        const int nb = t >> 2, kb = t & 3;
        const int col = (r >> 5) * U_N + nb * 32 + (r & 31);
        short8_t o;
#pragma unroll
        for (int j = 0; j < 8; ++j)
            o[j] = (short)f2bf(kern[(size_t)(kb * 64 + kc * 8 + j) * 2560 + col]);
        *reinterpret_cast<short8_t*>(ksw + (size_t)t * 10240 + SWZ(r, kc)) = o;
    } else {                                // ---- rk (transpose) ----
        const int c2 = c - 475136;
        const int t = c2 / 768, q = c2 - t * 768;
        const int kc = q / 96, r = q - kc * 96;       // r = mat*32 + cc
        const int nb = t >> 3, kb = t & 7;
        const int col = (r >> 5) * U_N + nb * 32 + (r & 31);
        short8_t o;
#pragma unroll
        for (int j = 0; j < 8; ++j)
            o[j] = (short)f2bf(rk[(size_t)(kb * 64 + kc * 8 + j) * 1536 + col]);
        *reinterpret_cast<short8_t*>(rsw + (size_t)t * 6144 + SWZ(r, kc)) = o;
    }
}

// ---------------------------------------------------------------------------
// main fused kernel (r6 body + c0 prefetch + NEG_EPS fold)
// grid (16, 32) = 512 blocks (2/CU), 256 threads (4 waves)
// wave (wm,wn) = (wave>>1, wave&1) owns rows [64*wm,+64) x cols [16*wn,+16)
// of the 128x32 band, for every stacked gate matrix.
// ---------------------------------------------------------------------------
__global__ __launch_bounds__(256, 2) void tlstm_main(
    const unsigned short* __restrict__ xs,    // swizzled x tiles
    const unsigned short* __restrict__ hs,    // swizzled h0 tiles
    const unsigned short* __restrict__ ksw,   // swizzled kernel^T tiles
    const unsigned short* __restrict__ rsw,   // swizzled rk^T tiles
    const float* __restrict__ tvec,           // [4096]
    const float* __restrict__ c0,             // [4096][512]
    const float* __restrict__ ktime,          // [1536] cols [t1,t2,o]
    float* __restrict__ out)                  // h, then c_m
{
    // per buffer: A 8192 elems (16KB) + B 10240 elems (20KB) = 36KB; x2 = 72KB
    __shared__ __align__(16) unsigned short lds[2][18432];

    const int tid = threadIdx.x;
    const int wave = tid >> 6;
    const int lane = tid & 63;
    const int lr = lane & 15;
    const int lq = lane >> 4;
    const int wm = wave >> 1;                 // 0..1 : row half
    const int wn = wave & 1;                  // 0..1 : col half
    const int nb = blockIdx.x;
    const int rb = blockIdx.y;

    const int u = nb * 32 + wn * 16 + lr;     // output column

    // acc[m][p]: gate matrix m (0..4 = x@K gates, 5..7 = h0@RK gates),
    // row-fragment p (rows wm*64 + p*16), cols wn*16..+16
    f32x4_t acc[8][4];
#pragma unroll
    for (int m = 0; m < 8; ++m)
#pragma unroll
        for (int p = 0; p < 4; ++p)
            acc[m][p] = (f32x4_t){0.f, 0.f, 0.f, 0.f};

    float c0r[16];                            // c0 prefetch (issued at s=11)

    // ---- staging: linear global_load_lds, wave-uniform LDS dest ----
    // per-thread vmem ops: phase1 (s<4): 4 A + 5 B = 9; phase2: 4 A + 3 B = 7
    auto stage = [&](int s, int buf) {
        unsigned short* ab = &lds[buf][0];
        unsigned short* bb = &lds[buf][8192];
        if (s < 4) {
            const unsigned short* at = xs + (size_t)(rb * 4 + s) * 8192;
#pragma unroll
            for (int j = 0; j < 4; ++j)
                gl16(at + (j * 256 + tid) * 8, ab + (j * 256 + wave * 64) * 8);
            const unsigned short* bt = ksw + (size_t)(nb * 4 + s) * 10240;
#pragma unroll
            for (int j = 0; j < 5; ++j)
                gl16(bt + (j * 256 + tid) * 8, bb + (j * 256 + wave * 64) * 8);
        } else {
            const unsigned short* at = hs + (size_t)(rb * 8 + (s - 4)) * 8192;
#pragma unroll
            for (int j = 0; j < 4; ++j)
                gl16(at + (j * 256 + tid) * 8, ab + (j * 256 + wave * 64) * 8);
            const unsigned short* bt = rsw + (size_t)(nb * 8 + (s - 4)) * 6144;
#pragma unroll
            for (int j = 0; j < 3; ++j)
                gl16(bt + (j * 256 + tid) * 8, bb + (j * 256 + wave * 64) * 8);
        }
    };

    auto compute1 = [&](int buf) {      // x @ kernel -> acc[0..4]
        const unsigned short* ab = &lds[buf][0];
        const unsigned short* bb = &lds[buf][8192];
#pragma unroll
        for (int ks = 0; ks < 2; ++ks) {
            const int kc = ks * 4 + lq;
            short8_t a[4];
#pragma unroll
            for (int p = 0; p < 4; ++p)
                a[p] = *reinterpret_cast<const short8_t*>(ab + SWZ(wm * 64 + p * 16 + lr, kc));
#pragma unroll
            for (int m = 0; m < 5; ++m) {
                const int r = m * 32 + wn * 16 + lr;
                short8_t b = *reinterpret_cast<const short8_t*>(bb + SWZ(r, kc));
#pragma unroll
                for (int p = 0; p < 4; ++p)
                    acc[m][p] = __builtin_amdgcn_mfma_f32_16x16x32_bf16(a[p], b, acc[m][p], 0, 0, 0);
            }
        }
    };

    auto compute2 = [&](int buf) {      // h0 @ rk -> acc[5..7]
        const unsigned short* ab = &lds[buf][0];
        const unsigned short* bb = &lds[buf][8192];
#pragma unroll
        for (int ks = 0; ks < 2; ++ks) {
            const int kc = ks * 4 + lq;
            short8_t a[4];
#pragma unroll
            for (int p = 0; p < 4; ++p)
                a[p] = *reinterpret_cast<const short8_t*>(ab + SWZ(wm * 64 + p * 16 + lr, kc));
#pragma unroll
            for (int m = 0; m < 3; ++m) {
                const int r = m * 32 + wn * 16 + lr;
                short8_t b = *reinterpret_cast<const short8_t*>(bb + SWZ(r, kc));
#pragma unroll
                for (int p = 0; p < 4; ++p)
                    acc[5 + m][p] = __builtin_amdgcn_mfma_f32_16x16x32_bf16(a[p], b, acc[5 + m][p], 0, 0, 0);
            }
        }
    };

    // step body for tile S: wait until tile S's loads landed (leave the NV
    // just-issued loads of tile S+1 [+ c0] in flight), sync, compute, sync.
#define K_BODY(S, NV, CF)                                  \
    {                                                      \
        WAIT_VM(NV);                                       \
        __builtin_amdgcn_s_barrier();                      \
        __builtin_amdgcn_sched_barrier(0);                 \
        CF((S) & 1);                                       \
        __builtin_amdgcn_sched_barrier(0);                 \
        __builtin_amdgcn_s_barrier();                      \
        __builtin_amdgcn_sched_barrier(0);                 \
    }

    // ---- counted-vmcnt pipelined K-loop: 12 steps ----
    // per-thread load counts: L = [9,9,9,9,7,7,7,7,7,7,7,7]; c0 (16) after
    // stage(11) -> K_BODY(10) leaves t11(7)+c0(16)=23; K_BODY(11) leaves 16;
    // compiler inserts the final vmcnt wait before the epilogue reads c0r.
    stage(0, 0);
    stage(1, 1);   K_BODY(0, 9, compute1);
    stage(2, 0);   K_BODY(1, 9, compute1);
    stage(3, 1);   K_BODY(2, 9, compute1);
    stage(4, 0);   K_BODY(3, 7, compute1);
    stage(5, 1);   K_BODY(4, 7, compute2);
    stage(6, 0);   K_BODY(5, 7, compute2);
    stage(7, 1);   K_BODY(6, 7, compute2);
    stage(8, 0);   K_BODY(7, 7, compute2);
    stage(9, 1);   K_BODY(8, 7, compute2);
    stage(10, 0);  K_BODY(9, 7, compute2);
    stage(11, 1);
    __builtin_amdgcn_sched_barrier(0);   // pin: c0 loads AFTER stage(11) in FIFO
#pragma unroll
    for (int p = 0; p < 4; ++p)
#pragma unroll
        for (int i2 = 0; i2 < 4; ++i2) {
            const int b = rb * 128 + wm * 64 + p * 16 + lq * 4 + i2;
            c0r[p * 4 + i2] = c0[(size_t)b * U_N + u];
        }
    __builtin_amdgcn_sched_barrier(0);
    K_BODY(10, 23, compute2);            // t10 done; t11(7)+c0(16) in flight
    K_BODY(11, 16, compute2);            // t11 done; c0(16) in flight

    // ---- epilogue: TimeLSTM elementwise (fp32) ----
    // t1_constraint: sigmoid output is always > -1e-5 -> constant -1e-5.
    const float NEG_EPS = -1e-5f;
    const float kt1 = ktime[u];
    const float kt2 = ktime[U_N + u];
    const float kto = ktime[2 * U_N + u];
#pragma unroll
    for (int p = 0; p < 4; ++p)
#pragma unroll
        for (int i2 = 0; i2 < 4; ++i2) {
            const int b = rb * 128 + wm * 64 + p * 16 + lq * 4 + i2;
            const float tb = tvec[b];
            const float c0v = c0r[p * 4 + i2];
            const float x_i  = acc[0][p][i2];
            const float x_c  = acc[1][p][i2];
            const float x_o  = acc[2][p][i2];
            const float x_t1 = acc[3][p][i2];
            const float x_t2 = acc[4][p][i2];
            const float r_i  = acc[5][p][i2];
            const float r_c  = acc[6][p][i2];
            const float r_o  = acc[7][p][i2];

            const float ig  = sigf(x_i + r_i);
            const float t1v = sigf(x_t1 + sigf(tb * kt1));
            const float t2v = sigf(x_t2 + sigf(tb * kt2));
            const float ct  = tanhfast(x_c + r_c);
            const float cm_ = (1.f - ig * t1v) * c0v + ig * ct * NEG_EPS;
            const float cm  = (1.f - ig) * c0v + ig * ct * t2v;
            const float og  = sigf(x_o + r_o + tb * kto);

            out[(size_t)b * U_N + u] = tanhfast(cm_) * og;
            out[(size_t)B_N * U_N + (size_t)b * U_N + u] = cm;
        }
}

// ---------------------------------------------------------------------------
extern "C" void kernel_launch(void* const* d_in, const int* in_sizes, int n_in,
                              void* d_out, int out_size, void* d_ws, size_t ws_size,
                              hipStream_t stream) {
    const float* x     = (const float*)d_in[0];   // [4096][256]
    const float* t     = (const float*)d_in[1];   // [4096][1]
    const float* h0    = (const float*)d_in[2];   // [4096][512]
    const float* c0    = (const float*)d_in[3];   // [4096][512]
    const float* kern  = (const float*)d_in[4];   // [256][2560]
    const float* rk    = (const float*)d_in[5];   // [512][1536]
    const float* ktime = (const float*)d_in[6];   // [1][1536]
    float* out = (float*)d_out;

    // ws layout (bytes):
    //   xs  @ 0        : 4096*256*2  = 2,097,152  (swizzled 128x64 tiles)
    //   hs  @ 2097152  : 4096*512*2  = 4,194,304
    //   ksw @ 6291456  : 2560*256*2  = 1,310,720  (swizzled 160x64 tiles)
    //   rsw @ 7602176  : 1536*512*2  = 1,572,864  (swizzled  96x64 tiles)
    unsigned short* xs  = (unsigned short*)d_ws;
    unsigned short* hs  = (unsigned short*)((char*)d_ws + 2097152);
    unsigned short* ksw = (unsigned short*)((char*)d_ws + 6291456);
    unsigned short* rsw = (unsigned short*)((char*)d_ws + 7602176);

    prep<<<2240, 256, 0, stream>>>(x, h0, kern, rk, xs, hs, ksw, rsw);
    tlstm_main<<<dim3(16, 32), 256, 0, stream>>>(
        xs, hs, ksw, rsw, t, c0, ktime, out);
}